// Round 5
// baseline (10733.020 us; speedup 1.0000x reference)
//
#include <hip/hip_runtime.h>
#include <hip/hip_bf16.h>

// Problem constants
#define BB 64
#define TT 256
#define HH 512
#define EE 256
#define NTAGS 50
#define BT (BB * TT)  // 16384
#define SBLK 128      // scan grid: 64 blocks per direction, 8 hidden units each

typedef _Float16 f16;
typedef __attribute__((ext_vector_type(4))) _Float16 half4;
typedef __attribute__((ext_vector_type(8))) _Float16 half8;
typedef __attribute__((ext_vector_type(8))) short short8;
typedef __attribute__((ext_vector_type(4))) float f32x4;
typedef __hip_bfloat16 bf16;

__device__ __forceinline__ float sigm(float x) {
    return 1.f / (1.f + __expf(-x));
}
__device__ __forceinline__ float tanh_f(float x) {
    float ax = fabsf(x);
    float e = __expf(2.f * ax);
    float t = 1.f - 2.f / (e + 1.f);
    return x < 0.f ? -t : t;
}
__device__ __forceinline__ short f2bs(float f) {
    return (short)__bfloat16_as_ushort(__float2bfloat16(f));
}
// split 8 fp32 values (in regs) into bf16 hi + bf16 lo(residual)
__device__ __forceinline__ void split8v(const float* vv, bf16* hi, bf16* lo) {
    short8 h8, l8;
#pragma unroll
    for (int j = 0; j < 8; ++j) {
        bf16 h = __float2bfloat16(vv[j]);
        h8[j] = (short)__bfloat16_as_ushort(h);
        l8[j] = f2bs(vv[j] - __bfloat162float(h));
    }
    *(short8*)hi = h8;
    *(short8*)lo = l8;
}
// split 8 consecutive fp32 from memory
__device__ __forceinline__ void split8(const float* p, bf16* hi, bf16* lo) {
    float4 v0 = *(const float4*)p;
    float4 v1 = *(const float4*)(p + 4);
    float vv[8] = {v0.x, v0.y, v0.z, v0.w, v1.x, v1.y, v1.z, v1.w};
    split8v(vv, hi, lo);
}
// split 8 consecutive f16 from memory
__device__ __forceinline__ void split8h(const f16* p, bf16* hi, bf16* lo) {
    half8 a = *(const half8*)p;
    float vv[8];
#pragma unroll
    for (int j = 0; j < 8; ++j) vv[j] = (float)a[j];
    split8v(vv, hi, lo);
}

// ---------------------------------------------------------------------------
__global__ void bar_init(int* __restrict__ bar) {
    if (threadIdx.x < 2) bar[threadIdx.x] = 0;
}

// ---------------------------------------------------------------------------
// embedding gather fp32 -> f16 storage: e[idx][:] = f16(emb[x[idx]][:])
__global__ __launch_bounds__(256) void embed_gather(
    const int* __restrict__ x, const float* __restrict__ emb, f16* __restrict__ e) {
    int idx = blockIdx.x * 4 + (threadIdx.x >> 6);
    int lane = threadIdx.x & 63;
    int tok = x[idx];
    float4 v = *(const float4*)(emb + (size_t)tok * EE + lane * 4);
    half4 o;
    o[0] = (f16)v.x; o[1] = (f16)v.y; o[2] = (f16)v.z; o[3] = (f16)v.w;
    *(half4*)(e + (size_t)idx * EE + lane * 4) = o;
}

// ---------------------------------------------------------------------------
// C[M,N] = A[M,K] @ W[N,K]^T + bias[N].  A: f16 storage, W/bias fp32.
// Both A and W are split into bf16 hi+lo in LDS; 3 MFMA products
// (AhWh + AhWl + AlWh) give ~fp32-accurate results.  Output f16.
// 128x128 tile, BK=64, 4 waves each 64x64 (4x4 mfma 16x16x32 tiles).
__global__ __launch_bounds__(256) void gemm_bt(
    const f16* __restrict__ A, const float* __restrict__ W,
    const float* __restrict__ bias, f16* __restrict__ C,
    int M, int N, int K) {
    __shared__ bf16 Ah[128][72], Al[128][72];  // +8 pad
    __shared__ bf16 Wh[128][72], Wl[128][72];
    const int m0 = blockIdx.x * 128;
    const int n0 = blockIdx.y * 128;
    const int tid = threadIdx.x;
    const int wave = tid >> 6;
    const int lane = tid & 63;
    const int lrow = lane & 15;
    const int quad = lane >> 4;
    const int msub = (wave >> 1) * 64;
    const int nsub = (wave & 1) * 64;

    f32x4 acc[4][4];
#pragma unroll
    for (int i = 0; i < 4; ++i)
#pragma unroll
        for (int j = 0; j < 4; ++j) acc[i][j] = (f32x4){0.f, 0.f, 0.f, 0.f};

    for (int k0 = 0; k0 < K; k0 += 64) {
        __syncthreads();
#pragma unroll
        for (int c = 0; c < 4; ++c) {
            int f = c * 256 + tid;     // 1024 chunks: 128 rows x 8 chunks of 8
            int row = f >> 3;
            int kc = f & 7;
            split8h(A + (size_t)(m0 + row) * K + k0 + kc * 8,
                    &Ah[row][kc * 8], &Al[row][kc * 8]);
            split8(W + (size_t)(n0 + row) * K + k0 + kc * 8,
                   &Wh[row][kc * 8], &Wl[row][kc * 8]);
        }
        __syncthreads();
#pragma unroll
        for (int ks = 0; ks < 2; ++ks) {
            short8 ah[4], al[4], bh[4], bl[4];
#pragma unroll
            for (int i = 0; i < 4; ++i) {
                ah[i] = *(const short8*)&Ah[msub + i * 16 + lrow][ks * 32 + quad * 8];
                al[i] = *(const short8*)&Al[msub + i * 16 + lrow][ks * 32 + quad * 8];
            }
#pragma unroll
            for (int j = 0; j < 4; ++j) {
                bh[j] = *(const short8*)&Wh[nsub + j * 16 + lrow][ks * 32 + quad * 8];
                bl[j] = *(const short8*)&Wl[nsub + j * 16 + lrow][ks * 32 + quad * 8];
            }
#pragma unroll
            for (int i = 0; i < 4; ++i)
#pragma unroll
                for (int j = 0; j < 4; ++j) {
                    acc[i][j] = __builtin_amdgcn_mfma_f32_16x16x32_bf16(ah[i], bh[j], acc[i][j], 0, 0, 0);
                    acc[i][j] = __builtin_amdgcn_mfma_f32_16x16x32_bf16(ah[i], bl[j], acc[i][j], 0, 0, 0);
                    acc[i][j] = __builtin_amdgcn_mfma_f32_16x16x32_bf16(al[i], bh[j], acc[i][j], 0, 0, 0);
                }
        }
    }

#pragma unroll
    for (int j = 0; j < 4; ++j) {
        int n = n0 + nsub + j * 16 + lrow;
        float bv = bias[n];
#pragma unroll
        for (int i = 0; i < 4; ++i)
#pragma unroll
            for (int r = 0; r < 4; ++r) {
                int m = m0 + msub + i * 16 + quad * 4 + r;
                C[(size_t)m * N + n] = (f16)(acc[i][j][r] + bv);
            }
    }
}

// ---------------------------------------------------------------------------
// Classifier: logits[BT,50] fp32 = out2[BT,1024] @ cls_w[50,1024]^T + cls_b.
// A (f16 storage) and W (fp32) both hi/lo split; 3 products.
__global__ __launch_bounds__(256) void cls_gemm(
    const f16* __restrict__ A, const float* __restrict__ W,
    const float* __restrict__ bias, float* __restrict__ C) {
    __shared__ bf16 Ah[128][72], Al[128][72];
    __shared__ bf16 Wh[64][72], Wl[64][72];
    const int m0 = blockIdx.x * 128;
    const int tid = threadIdx.x;
    const int wave = tid >> 6;
    const int lane = tid & 63;
    const int lrow = lane & 15;
    const int quad = lane >> 4;
    const int msub = wave * 32;

    f32x4 acc[2][4];
#pragma unroll
    for (int i = 0; i < 2; ++i)
#pragma unroll
        for (int j = 0; j < 4; ++j) acc[i][j] = (f32x4){0.f, 0.f, 0.f, 0.f};

    for (int k0 = 0; k0 < 1024; k0 += 64) {
        __syncthreads();
#pragma unroll
        for (int c = 0; c < 4; ++c) {
            int f = c * 256 + tid;   // 1024 chunks: 128 rows x 8
            int row = f >> 3;
            int kc = f & 7;
            split8h(A + (size_t)(m0 + row) * 1024 + k0 + kc * 8,
                    &Ah[row][kc * 8], &Al[row][kc * 8]);
        }
#pragma unroll
        for (int c = 0; c < 2; ++c) {
            int f = c * 256 + tid;   // 512 chunks: 64 rows x 8
            int row = f >> 3;
            int kc = f & 7;
            int wr = row < NTAGS ? row : NTAGS - 1;
            split8(W + (size_t)wr * 1024 + k0 + kc * 8,
                   &Wh[row][kc * 8], &Wl[row][kc * 8]);
        }
        __syncthreads();
#pragma unroll
        for (int ks = 0; ks < 2; ++ks) {
            short8 ah[2], al[2], bh[4], bl[4];
#pragma unroll
            for (int i = 0; i < 2; ++i) {
                ah[i] = *(const short8*)&Ah[msub + i * 16 + lrow][ks * 32 + quad * 8];
                al[i] = *(const short8*)&Al[msub + i * 16 + lrow][ks * 32 + quad * 8];
            }
#pragma unroll
            for (int j = 0; j < 4; ++j) {
                bh[j] = *(const short8*)&Wh[j * 16 + lrow][ks * 32 + quad * 8];
                bl[j] = *(const short8*)&Wl[j * 16 + lrow][ks * 32 + quad * 8];
            }
#pragma unroll
            for (int i = 0; i < 2; ++i)
#pragma unroll
                for (int j = 0; j < 4; ++j) {
                    acc[i][j] = __builtin_amdgcn_mfma_f32_16x16x32_bf16(ah[i], bh[j], acc[i][j], 0, 0, 0);
                    acc[i][j] = __builtin_amdgcn_mfma_f32_16x16x32_bf16(ah[i], bl[j], acc[i][j], 0, 0, 0);
                    acc[i][j] = __builtin_amdgcn_mfma_f32_16x16x32_bf16(al[i], bh[j], acc[i][j], 0, 0, 0);
                }
        }
    }

#pragma unroll
    for (int j = 0; j < 4; ++j) {
        int n = j * 16 + lrow;
        if (n < NTAGS) {
            float bv = bias[n];
#pragma unroll
            for (int i = 0; i < 2; ++i)
#pragma unroll
                for (int r = 0; r < 4; ++r) {
                    int m = m0 + msub + i * 16 + quad * 4 + r;
                    C[(size_t)m * NTAGS + n] = acc[i][j][r] + bv;
                }
        }
    }
}

// ---------------------------------------------------------------------------
// Persistent masked BiLSTM scan, fp32-accurate recurrence via bf16 hi/lo.
// 128 blocks x 256 threads: dir = blk>>6, sl = blk&63 -> owns 8 hidden units
// (32 gate rows).  w_hh slice in LDS as bf16 hi+lo; h exchanged via global
// bf16 hi/lo double buffer + device-scope grid barrier; c fp32 in LDS.
// Padded positions (t >= len) are written as zeros (no pre-zero pass).
__global__ __launch_bounds__(256) void lstm_scan(
    const f16* __restrict__ xpre_f, const f16* __restrict__ xpre_b,
    const float* __restrict__ whh_f, const float* __restrict__ whh_b,
    const int* __restrict__ lengths,
    f16* __restrict__ out,      // [BT, 2H]
    bf16* __restrict__ hbuf,    // [dir][parity][hi/lo][64][512]
    int* __restrict__ bar) {
    __shared__ bf16 w_hi[32][520];   // 32 gate rows x 512, +8 pad
    __shared__ bf16 w_lo[32][520];
    __shared__ float gat[64][40];    // [batch][gate*8+u]
    __shared__ float h_loc[64][8];
    __shared__ float c_loc[64][8];
    __shared__ int len_s[64];

    const int dir = blockIdx.x >> 6;
    const int sl = blockIdx.x & 63;
    const int tid = threadIdx.x;
    const int wave = tid >> 6;
    const int lane = tid & 63;
    const int lrow = lane & 15;
    const int quad = lane >> 4;

    const f16* xpre = dir ? xpre_b : xpre_f;
    const float* whh = dir ? whh_b : whh_f;
    bf16* hb = hbuf + (size_t)dir * 2 * 2 * BB * HH;

    // stage w_hh slice rows r = g*8+u  <-  whh[g*512 + sl*8 + u][:], hi/lo
    for (int f = tid; f < 32 * 64; f += 256) {
        int row = f >> 6;
        int c = f & 63;
        int g = row >> 3, u = row & 7;
        split8(whh + (size_t)(g * HH + sl * 8 + u) * HH + c * 8,
               &w_hi[row][c * 8], &w_lo[row][c * 8]);
    }
    if (tid < 64) len_s[tid] = lengths[tid];
    for (int r = tid; r < 512; r += 256) {
        h_loc[r >> 3][r & 7] = 0.f;
        c_loc[r >> 3][r & 7] = 0.f;
    }
    __syncthreads();

    for (int s = 0; s < TT; ++s) {
        if (s > 0) {
            const bf16* hp_hi = hb + (size_t)(((s & 1) ^ 1) * 2 + 0) * BB * HH;
            const bf16* hp_lo = hp_hi + BB * HH;
            f32x4 acc[2];
            acc[0] = (f32x4){0.f, 0.f, 0.f, 0.f};
            acc[1] = (f32x4){0.f, 0.f, 0.f, 0.f};
            const int b = wave * 16 + lrow;
            const size_t hoff = (size_t)b * HH;
#pragma unroll 4
            for (int ks = 0; ks < 16; ++ks) {
                short8 ahh = *(const short8*)(hp_hi + hoff + ks * 32 + quad * 8);
                short8 all = *(const short8*)(hp_lo + hoff + ks * 32 + quad * 8);
#pragma unroll
                for (int nt = 0; nt < 2; ++nt) {
                    short8 bhh = *(const short8*)&w_hi[nt * 16 + lrow][ks * 32 + quad * 8];
                    short8 bll = *(const short8*)&w_lo[nt * 16 + lrow][ks * 32 + quad * 8];
                    acc[nt] = __builtin_amdgcn_mfma_f32_16x16x32_bf16(ahh, bhh, acc[nt], 0, 0, 0);
                    acc[nt] = __builtin_amdgcn_mfma_f32_16x16x32_bf16(all, bhh, acc[nt], 0, 0, 0);
                    acc[nt] = __builtin_amdgcn_mfma_f32_16x16x32_bf16(ahh, bll, acc[nt], 0, 0, 0);
                }
            }
#pragma unroll
            for (int nt = 0; nt < 2; ++nt)
#pragma unroll
                for (int r = 0; r < 4; ++r)
                    gat[wave * 16 + quad * 4 + r][nt * 16 + lrow] = acc[nt][r];
        }
        __syncthreads();

        bf16* hc_hi = hb + (size_t)((s & 1) * 2 + 0) * BB * HH;
        bf16* hc_lo = hc_hi + BB * HH;
#pragma unroll
        for (int rep = 0; rep < 2; ++rep) {
            int idx = rep * 256 + tid;
            int b = idx >> 3, u = idx & 7;
            int len = len_s[b];
            if (s < len) {
                int ta = dir ? (len - 1 - s) : s;
                const f16* xp = xpre + (size_t)(b * TT + ta) * 2048 + sl * 8 + u;
                float zi = (float)xp[0];
                float zf = (float)xp[512];
                float zg = (float)xp[1024];
                float zo = (float)xp[1536];
                if (s > 0) {
                    zi += gat[b][u];
                    zf += gat[b][8 + u];
                    zg += gat[b][16 + u];
                    zo += gat[b][24 + u];
                }
                float ig = sigm(zi), fg = sigm(zf);
                float gg = tanh_f(zg), og = sigm(zo);
                float c = fg * c_loc[b][u] + ig * gg;
                float h = og * tanh_f(c);
                c_loc[b][u] = c;
                h_loc[b][u] = h;
                out[(size_t)(b * TT + ta) * 1024 + dir * 512 + sl * 8 + u] = (f16)h;
            } else {
                // padded position t = s: reference holds exact zeros
                out[(size_t)(b * TT + s) * 1024 + dir * 512 + sl * 8 + u] = (f16)0.f;
            }
            // always publish hi/lo (carried h for masked rows)
            float h = h_loc[b][u];
            bf16 hh = __float2bfloat16(h);
            float rest = h - __bfloat162float(hh);
            hc_hi[(size_t)b * HH + sl * 8 + u] = hh;
            hc_lo[(size_t)b * HH + sl * 8 + u] = __float2bfloat16(rest);
        }

        // grid barrier (device scope); SBLK blocks
        __syncthreads();
        if (tid == 0) {
            __threadfence();
            int g = __hip_atomic_load(&bar[1], __ATOMIC_RELAXED, __HIP_MEMORY_SCOPE_AGENT);
            int a = __hip_atomic_fetch_add(&bar[0], 1, __ATOMIC_ACQ_REL, __HIP_MEMORY_SCOPE_AGENT);
            if (a == SBLK - 1) {
                __hip_atomic_store(&bar[0], 0, __ATOMIC_RELAXED, __HIP_MEMORY_SCOPE_AGENT);
                __hip_atomic_fetch_add(&bar[1], 1, __ATOMIC_RELEASE, __HIP_MEMORY_SCOPE_AGENT);
            } else {
                while (__hip_atomic_load(&bar[1], __ATOMIC_ACQUIRE, __HIP_MEMORY_SCOPE_AGENT) == g) {
                    __builtin_amdgcn_s_sleep(1);
                }
            }
        }
        __syncthreads();
    }
}

// ---------------------------------------------------------------------------
extern "C" void kernel_launch(void* const* d_in, const int* in_sizes, int n_in,
                              void* d_out, int out_size, void* d_ws, size_t ws_size,
                              hipStream_t stream) {
    const int* x = (const int*)d_in[0];
    const int* lengths = (const int*)d_in[1];
    const float* emb = (const float*)d_in[2];
    const float* w_ih_f1 = (const float*)d_in[3];
    const float* w_hh_f1 = (const float*)d_in[4];
    const float* b_f1 = (const float*)d_in[5];
    const float* w_ih_b1 = (const float*)d_in[6];
    const float* w_hh_b1 = (const float*)d_in[7];
    const float* b_b1 = (const float*)d_in[8];
    const float* w_ih_f2 = (const float*)d_in[9];
    const float* w_hh_f2 = (const float*)d_in[10];
    const float* b_f2 = (const float*)d_in[11];
    const float* w_ih_b2 = (const float*)d_in[12];
    const float* w_hh_b2 = (const float*)d_in[13];
    const float* b_b2 = (const float*)d_in[14];
    const float* cls_w = (const float*)d_in[15];
    const float* cls_b = (const float*)d_in[16];
    float* logits = (float*)d_out;

    // workspace layout (bytes) — max touched offset 184,549,376 (~176 MB),
    // below the round-2-proven 200.25 MB envelope.
    char* ws = (char*)d_ws;
    int* bar = (int*)ws;                        // 0 .. 4 KB
    bf16* hbuf = (bf16*)(ws + 4096);            // 4 KB .. ~1.05 MB
    f16* e = (f16*)(ws + 2097152);              // 2 MB .. 10 MB
    f16* xpre_f = (f16*)(ws + 16777216);        // 16 MB .. 80 MB
    f16* xpre_b = (f16*)(ws + 83886080);        // 80 MB .. 144 MB
    f16* out1 = (f16*)(ws + 150994944);         // 144 MB .. 176 MB
    f16* out2 = out1;  // alias: out1 dead once layer-2 GEMMs complete

    bar_init<<<1, 64, 0, stream>>>(bar);
    embed_gather<<<BT / 4, 256, 0, stream>>>(x, emb, e);

    dim3 g1(BT / 128, 2048 / 128);
    gemm_bt<<<g1, 256, 0, stream>>>(e, w_ih_f1, b_f1, xpre_f, BT, 2048, EE);
    gemm_bt<<<g1, 256, 0, stream>>>(e, w_ih_b1, b_b1, xpre_b, BT, 2048, EE);
    lstm_scan<<<SBLK, 256, 0, stream>>>(xpre_f, xpre_b, w_hh_f1, w_hh_b1,
                                        lengths, out1, hbuf, bar);

    gemm_bt<<<g1, 256, 0, stream>>>(out1, w_ih_f2, b_f2, xpre_f, BT, 2048, 2 * HH);
    gemm_bt<<<g1, 256, 0, stream>>>(out1, w_ih_b2, b_b2, xpre_b, BT, 2048, 2 * HH);
    lstm_scan<<<SBLK, 256, 0, stream>>>(xpre_f, xpre_b, w_hh_f2, w_hh_b2,
                                        lengths, out2, hbuf, bar);

    cls_gemm<<<BT / 128, 256, 0, stream>>>(out2, cls_w, cls_b, logits);
}

// Round 6
// 6444.110 us; speedup vs baseline: 1.6656x; 1.6656x over previous
//
#include <hip/hip_runtime.h>
#include <hip/hip_bf16.h>

// Problem constants
#define BB 64
#define TT 256
#define HH 512
#define EE 256
#define NTAGS 50
#define BT (BB * TT)  // 16384
#define SBLK 128      // scan grid: 64 blocks per direction, 8 hidden units each

typedef _Float16 f16;
typedef __attribute__((ext_vector_type(2))) _Float16 half2v;
typedef __attribute__((ext_vector_type(4))) _Float16 half4;
typedef __attribute__((ext_vector_type(8))) _Float16 half8;
typedef __attribute__((ext_vector_type(8))) short short8;
typedef __attribute__((ext_vector_type(4))) float f32x4;
typedef __hip_bfloat16 bf16;

__device__ __forceinline__ float sigm(float x) {
    return 1.f / (1.f + __expf(-x));
}
__device__ __forceinline__ float tanh_f(float x) {
    float ax = fabsf(x);
    float e = __expf(2.f * ax);
    float t = 1.f - 2.f / (e + 1.f);
    return x < 0.f ? -t : t;
}
__device__ __forceinline__ short f2bs(float f) {
    return (short)__bfloat16_as_ushort(__float2bfloat16(f));
}
// split 8 fp32 values (in regs) into bf16 hi + bf16 lo(residual)
__device__ __forceinline__ void split8v(const float* vv, bf16* hi, bf16* lo) {
    short8 h8, l8;
#pragma unroll
    for (int j = 0; j < 8; ++j) {
        bf16 h = __float2bfloat16(vv[j]);
        h8[j] = (short)__bfloat16_as_ushort(h);
        l8[j] = f2bs(vv[j] - __bfloat162float(h));
    }
    *(short8*)hi = h8;
    *(short8*)lo = l8;
}
__device__ __forceinline__ void split8(const float* p, bf16* hi, bf16* lo) {
    float4 v0 = *(const float4*)p;
    float4 v1 = *(const float4*)(p + 4);
    float vv[8] = {v0.x, v0.y, v0.z, v0.w, v1.x, v1.y, v1.z, v1.w};
    split8v(vv, hi, lo);
}
__device__ __forceinline__ void split8h(const f16* p, bf16* hi, bf16* lo) {
    half8 a = *(const half8*)p;
    float vv[8];
#pragma unroll
    for (int j = 0; j < 8; ++j) vv[j] = (float)a[j];
    split8v(vv, hi, lo);
}

// ---------------------------------------------------------------------------
__global__ void bar_init(int* __restrict__ bar) {
    if (threadIdx.x < 2) bar[threadIdx.x] = 0;
}

// ---------------------------------------------------------------------------
// embedding gather fp32 -> f16 storage
__global__ __launch_bounds__(256) void embed_gather(
    const int* __restrict__ x, const float* __restrict__ emb, f16* __restrict__ e) {
    int idx = blockIdx.x * 4 + (threadIdx.x >> 6);
    int lane = threadIdx.x & 63;
    int tok = x[idx];
    float4 v = *(const float4*)(emb + (size_t)tok * EE + lane * 4);
    half4 o;
    o[0] = (f16)v.x; o[1] = (f16)v.y; o[2] = (f16)v.z; o[3] = (f16)v.w;
    *(half4*)(e + (size_t)idx * EE + lane * 4) = o;
}

// ---------------------------------------------------------------------------
// C[M,N] = A[M,K] @ W[N,K]^T + bias[N].  A: f16 storage, W/bias fp32.
// Both split to bf16 hi+lo in LDS; 3 MFMA products -> ~fp32 accuracy. f16 out.
__global__ __launch_bounds__(256) void gemm_bt(
    const f16* __restrict__ A, const float* __restrict__ W,
    const float* __restrict__ bias, f16* __restrict__ C,
    int M, int N, int K) {
    __shared__ bf16 Ah[128][72], Al[128][72];
    __shared__ bf16 Wh[128][72], Wl[128][72];
    const int m0 = blockIdx.x * 128;
    const int n0 = blockIdx.y * 128;
    const int tid = threadIdx.x;
    const int wave = tid >> 6;
    const int lane = tid & 63;
    const int lrow = lane & 15;
    const int quad = lane >> 4;
    const int msub = (wave >> 1) * 64;
    const int nsub = (wave & 1) * 64;

    f32x4 acc[4][4];
#pragma unroll
    for (int i = 0; i < 4; ++i)
#pragma unroll
        for (int j = 0; j < 4; ++j) acc[i][j] = (f32x4){0.f, 0.f, 0.f, 0.f};

    for (int k0 = 0; k0 < K; k0 += 64) {
        __syncthreads();
#pragma unroll
        for (int c = 0; c < 4; ++c) {
            int f = c * 256 + tid;
            int row = f >> 3;
            int kc = f & 7;
            split8h(A + (size_t)(m0 + row) * K + k0 + kc * 8,
                    &Ah[row][kc * 8], &Al[row][kc * 8]);
            split8(W + (size_t)(n0 + row) * K + k0 + kc * 8,
                   &Wh[row][kc * 8], &Wl[row][kc * 8]);
        }
        __syncthreads();
#pragma unroll
        for (int ks = 0; ks < 2; ++ks) {
            short8 ah[4], al[4], bh[4], bl[4];
#pragma unroll
            for (int i = 0; i < 4; ++i) {
                ah[i] = *(const short8*)&Ah[msub + i * 16 + lrow][ks * 32 + quad * 8];
                al[i] = *(const short8*)&Al[msub + i * 16 + lrow][ks * 32 + quad * 8];
            }
#pragma unroll
            for (int j = 0; j < 4; ++j) {
                bh[j] = *(const short8*)&Wh[nsub + j * 16 + lrow][ks * 32 + quad * 8];
                bl[j] = *(const short8*)&Wl[nsub + j * 16 + lrow][ks * 32 + quad * 8];
            }
#pragma unroll
            for (int i = 0; i < 4; ++i)
#pragma unroll
                for (int j = 0; j < 4; ++j) {
                    acc[i][j] = __builtin_amdgcn_mfma_f32_16x16x32_bf16(ah[i], bh[j], acc[i][j], 0, 0, 0);
                    acc[i][j] = __builtin_amdgcn_mfma_f32_16x16x32_bf16(ah[i], bl[j], acc[i][j], 0, 0, 0);
                    acc[i][j] = __builtin_amdgcn_mfma_f32_16x16x32_bf16(al[i], bh[j], acc[i][j], 0, 0, 0);
                }
        }
    }

#pragma unroll
    for (int j = 0; j < 4; ++j) {
        int n = n0 + nsub + j * 16 + lrow;
        float bv = bias[n];
#pragma unroll
        for (int i = 0; i < 4; ++i)
#pragma unroll
            for (int r = 0; r < 4; ++r) {
                int m = m0 + msub + i * 16 + quad * 4 + r;
                C[(size_t)m * N + n] = (f16)(acc[i][j][r] + bv);
            }
    }
}

// ---------------------------------------------------------------------------
// Classifier: logits[BT,50] fp32 = out2[BT,1024] @ cls_w[50,1024]^T + cls_b.
__global__ __launch_bounds__(256) void cls_gemm(
    const f16* __restrict__ A, const float* __restrict__ W,
    const float* __restrict__ bias, float* __restrict__ C) {
    __shared__ bf16 Ah[128][72], Al[128][72];
    __shared__ bf16 Wh[64][72], Wl[64][72];
    const int m0 = blockIdx.x * 128;
    const int tid = threadIdx.x;
    const int wave = tid >> 6;
    const int lane = tid & 63;
    const int lrow = lane & 15;
    const int quad = lane >> 4;
    const int msub = wave * 32;

    f32x4 acc[2][4];
#pragma unroll
    for (int i = 0; i < 2; ++i)
#pragma unroll
        for (int j = 0; j < 4; ++j) acc[i][j] = (f32x4){0.f, 0.f, 0.f, 0.f};

    for (int k0 = 0; k0 < 1024; k0 += 64) {
        __syncthreads();
#pragma unroll
        for (int c = 0; c < 4; ++c) {
            int f = c * 256 + tid;
            int row = f >> 3;
            int kc = f & 7;
            split8h(A + (size_t)(m0 + row) * 1024 + k0 + kc * 8,
                    &Ah[row][kc * 8], &Al[row][kc * 8]);
        }
#pragma unroll
        for (int c = 0; c < 2; ++c) {
            int f = c * 256 + tid;
            int row = f >> 3;
            int kc = f & 7;
            int wr = row < NTAGS ? row : NTAGS - 1;
            split8(W + (size_t)wr * 1024 + k0 + kc * 8,
                   &Wh[row][kc * 8], &Wl[row][kc * 8]);
        }
        __syncthreads();
#pragma unroll
        for (int ks = 0; ks < 2; ++ks) {
            short8 ah[2], al[2], bh[4], bl[4];
#pragma unroll
            for (int i = 0; i < 2; ++i) {
                ah[i] = *(const short8*)&Ah[msub + i * 16 + lrow][ks * 32 + quad * 8];
                al[i] = *(const short8*)&Al[msub + i * 16 + lrow][ks * 32 + quad * 8];
            }
#pragma unroll
            for (int j = 0; j < 4; ++j) {
                bh[j] = *(const short8*)&Wh[j * 16 + lrow][ks * 32 + quad * 8];
                bl[j] = *(const short8*)&Wl[j * 16 + lrow][ks * 32 + quad * 8];
            }
#pragma unroll
            for (int i = 0; i < 2; ++i)
#pragma unroll
                for (int j = 0; j < 4; ++j) {
                    acc[i][j] = __builtin_amdgcn_mfma_f32_16x16x32_bf16(ah[i], bh[j], acc[i][j], 0, 0, 0);
                    acc[i][j] = __builtin_amdgcn_mfma_f32_16x16x32_bf16(ah[i], bl[j], acc[i][j], 0, 0, 0);
                    acc[i][j] = __builtin_amdgcn_mfma_f32_16x16x32_bf16(al[i], bh[j], acc[i][j], 0, 0, 0);
                }
        }
    }

#pragma unroll
    for (int j = 0; j < 4; ++j) {
        int n = j * 16 + lrow;
        if (n < NTAGS) {
            float bv = bias[n];
#pragma unroll
            for (int i = 0; i < 2; ++i)
#pragma unroll
                for (int r = 0; r < 4; ++r) {
                    int m = m0 + msub + i * 16 + quad * 4 + r;
                    C[(size_t)m * NTAGS + n] = acc[i][j][r] + bv;
                }
        }
    }
}

// ---------------------------------------------------------------------------
// Persistent masked BiLSTM scan, fence-free barrier.
// h exchange + barrier flags use relaxed AGENT-scope atomics (per-instruction
// device-coherent, bypass non-coherent per-XCD L2) -> NO L2 wb/inv cache ops
// in the steady state.  Ordering: h-stores drain at the s_waitcnt vmcnt(0)
// the compiler emits before s_barrier; then one relaxed atomicAdd arrival;
// monotonic generation counter for release (no reset race); spinners poll
// with relaxed loads.  xpre for step s+1 prefetched into regs during the wait.
__global__ __launch_bounds__(256) void lstm_scan(
    const f16* __restrict__ xpre_f, const f16* __restrict__ xpre_b,
    const float* __restrict__ whh_f, const float* __restrict__ whh_b,
    const int* __restrict__ lengths,
    f16* __restrict__ out,      // [BT, 2H]
    bf16* __restrict__ hbuf,    // [dir][parity][hi/lo][64][512]
    int* __restrict__ bar, int base) {
    __shared__ bf16 w_hi[32][520];   // 32 gate rows x 512, +8 pad
    __shared__ bf16 w_lo[32][520];
    __shared__ float gat[64][40];    // [batch][gate*8+u]
    __shared__ float h_loc[64][8];
    __shared__ float c_loc[64][8];
    __shared__ int len_s[64];

    const int dir = blockIdx.x >> 6;
    const int sl = blockIdx.x & 63;
    const int tid = threadIdx.x;
    const int wave = tid >> 6;
    const int lane = tid & 63;
    const int lrow = lane & 15;
    const int quad = lane >> 4;
    // gate-phase mapping: thread -> (batch, unit-pair)
    const int gb = tid >> 2;
    const int up = tid & 3;
    const int u0 = up * 2;

    const f16* xpre = dir ? xpre_b : xpre_f;
    const float* whh = dir ? whh_b : whh_f;
    bf16* hb = hbuf + (size_t)dir * 2 * 2 * BB * HH;
    int* cnt = &bar[0];
    int* gen = &bar[1];

    // stage w_hh slice rows r = g*8+u  <-  whh[g*512 + sl*8 + u][:], hi/lo
    for (int f = tid; f < 32 * 64; f += 256) {
        int row = f >> 6;
        int c = f & 63;
        int g = row >> 3, u = row & 7;
        split8(whh + (size_t)(g * HH + sl * 8 + u) * HH + c * 8,
               &w_hi[row][c * 8], &w_lo[row][c * 8]);
    }
    if (tid < 64) len_s[tid] = lengths[tid];
    for (int r = tid; r < 512; r += 256) {
        h_loc[r >> 3][r & 7] = 0.f;
        c_loc[r >> 3][r & 7] = 0.f;
    }
    __syncthreads();

    // prefetch xpre for s = 0 (len >= 1 always)
    float pr[2][4];
    {
        int len = len_s[gb];
        int ta = dir ? (len - 1) : 0;
        const f16* xp = xpre + (size_t)(gb * TT + ta) * 2048 + sl * 8 + u0;
        half2v g0 = *(const half2v*)(xp);
        half2v g1 = *(const half2v*)(xp + 512);
        half2v g2 = *(const half2v*)(xp + 1024);
        half2v g3 = *(const half2v*)(xp + 1536);
        pr[0][0] = (float)g0[0]; pr[1][0] = (float)g0[1];
        pr[0][1] = (float)g1[0]; pr[1][1] = (float)g1[1];
        pr[0][2] = (float)g2[0]; pr[1][2] = (float)g2[1];
        pr[0][3] = (float)g3[0]; pr[1][3] = (float)g3[1];
    }

    for (int s = 0; s < TT; ++s) {
        if (s > 0) {
            // wait for all blocks to finish step s-1
            if (tid == 0) {
                int target = base + s;
                while (__hip_atomic_load(gen, __ATOMIC_RELAXED,
                                         __HIP_MEMORY_SCOPE_AGENT) < target)
                    __builtin_amdgcn_s_sleep(1);
            }
            __syncthreads();
            __asm__ volatile("" ::: "memory");

            // gat[b][r] = h_prev[b][:] . w_hh_slice[r][:]  (hi/lo 3 products)
            const unsigned long long* hp_hi = (const unsigned long long*)
                (hb + (size_t)(((s & 1) ^ 1) * 2) * BB * HH);
            const unsigned long long* hp_lo = hp_hi + (BB * HH / 4);
            f32x4 acc[2];
            acc[0] = (f32x4){0.f, 0.f, 0.f, 0.f};
            acc[1] = (f32x4){0.f, 0.f, 0.f, 0.f};
            const int b = wave * 16 + lrow;
            const int bofs = b * 128;  // u64 units per h-row = 512/4
#pragma unroll 4
            for (int ks = 0; ks < 16; ++ks) {
                int idx = bofs + ks * 8 + quad * 2;
                union { unsigned long long q[2]; short8 v; } ua, ul;
                ua.q[0] = __hip_atomic_load((unsigned long long*)&hp_hi[idx],
                                            __ATOMIC_RELAXED, __HIP_MEMORY_SCOPE_AGENT);
                ua.q[1] = __hip_atomic_load((unsigned long long*)&hp_hi[idx + 1],
                                            __ATOMIC_RELAXED, __HIP_MEMORY_SCOPE_AGENT);
                ul.q[0] = __hip_atomic_load((unsigned long long*)&hp_lo[idx],
                                            __ATOMIC_RELAXED, __HIP_MEMORY_SCOPE_AGENT);
                ul.q[1] = __hip_atomic_load((unsigned long long*)&hp_lo[idx + 1],
                                            __ATOMIC_RELAXED, __HIP_MEMORY_SCOPE_AGENT);
                short8 ahh = ua.v;
                short8 all = ul.v;
#pragma unroll
                for (int nt = 0; nt < 2; ++nt) {
                    short8 bhh = *(const short8*)&w_hi[nt * 16 + lrow][ks * 32 + quad * 8];
                    short8 bll = *(const short8*)&w_lo[nt * 16 + lrow][ks * 32 + quad * 8];
                    acc[nt] = __builtin_amdgcn_mfma_f32_16x16x32_bf16(ahh, bhh, acc[nt], 0, 0, 0);
                    acc[nt] = __builtin_amdgcn_mfma_f32_16x16x32_bf16(all, bhh, acc[nt], 0, 0, 0);
                    acc[nt] = __builtin_amdgcn_mfma_f32_16x16x32_bf16(ahh, bll, acc[nt], 0, 0, 0);
                }
            }
#pragma unroll
            for (int nt = 0; nt < 2; ++nt)
#pragma unroll
                for (int r = 0; r < 4; ++r)
                    gat[wave * 16 + quad * 4 + r][nt * 16 + lrow] = acc[nt][r];
            __syncthreads();
        }

        // ---- gate phase: thread handles (gb, units u0,u0+1) ----
        unsigned int* hc_hi = (unsigned int*)(hb + (size_t)((s & 1) * 2) * BB * HH);
        unsigned int* hc_lo = hc_hi + (BB * HH / 2);
        {
            int len = len_s[gb];
            float h0 = h_loc[gb][u0];
            float h1 = h_loc[gb][u0 + 1];
            if (s < len) {
                int ta = dir ? (len - 1 - s) : s;
                float z0[4], z1[4];
#pragma unroll
                for (int g = 0; g < 4; ++g) { z0[g] = pr[0][g]; z1[g] = pr[1][g]; }
                if (s > 0) {
#pragma unroll
                    for (int g = 0; g < 4; ++g) {
                        z0[g] += gat[gb][g * 8 + u0];
                        z1[g] += gat[gb][g * 8 + u0 + 1];
                    }
                }
                float i0 = sigm(z0[0]), f0 = sigm(z0[1]);
                float g0 = tanh_f(z0[2]), o0 = sigm(z0[3]);
                float i1 = sigm(z1[0]), f1 = sigm(z1[1]);
                float g1 = tanh_f(z1[2]), o1 = sigm(z1[3]);
                float c0 = f0 * c_loc[gb][u0] + i0 * g0;
                float c1 = f1 * c_loc[gb][u0 + 1] + i1 * g1;
                h0 = o0 * tanh_f(c0);
                h1 = o1 * tanh_f(c1);
                c_loc[gb][u0] = c0; c_loc[gb][u0 + 1] = c1;
                h_loc[gb][u0] = h0; h_loc[gb][u0 + 1] = h1;
                half2v ov; ov[0] = (f16)h0; ov[1] = (f16)h1;
                *(half2v*)(out + (size_t)(gb * TT + ta) * 1024 + dir * 512 + sl * 8 + u0) = ov;
            } else {
                half2v zv; zv[0] = (f16)0.f; zv[1] = (f16)0.f;
                *(half2v*)(out + (size_t)(gb * TT + s) * 1024 + dir * 512 + sl * 8 + u0) = zv;
            }
            // publish hi/lo packed (always, carried h for masked rows)
            bf16 bh0 = __float2bfloat16(h0);
            bf16 bh1 = __float2bfloat16(h1);
            unsigned int hw = (unsigned int)__bfloat16_as_ushort(bh0) |
                              ((unsigned int)__bfloat16_as_ushort(bh1) << 16);
            float r0 = h0 - __bfloat162float(bh0);
            float r1 = h1 - __bfloat162float(bh1);
            unsigned int lw = (unsigned int)(unsigned short)f2bs(r0) |
                              ((unsigned int)(unsigned short)f2bs(r1) << 16);
            int widx = gb * (HH / 2) + sl * 4 + up;
            __hip_atomic_store(&hc_hi[widx], hw, __ATOMIC_RELAXED, __HIP_MEMORY_SCOPE_AGENT);
            __hip_atomic_store(&hc_lo[widx], lw, __ATOMIC_RELAXED, __HIP_MEMORY_SCOPE_AGENT);
        }
        __asm__ volatile("" ::: "memory");
        __syncthreads();  // compiler drains vmcnt(0) before s_barrier: h-stores done

        // arrive (one per block, monotonic count)
        if (tid == 0) {
            int old = __hip_atomic_fetch_add(cnt, 1, __ATOMIC_RELAXED,
                                             __HIP_MEMORY_SCOPE_AGENT);
            if (old == (base + s + 1) * SBLK - 1)
                __hip_atomic_fetch_add(gen, 1, __ATOMIC_RELAXED,
                                       __HIP_MEMORY_SCOPE_AGENT);
        }

        // prefetch xpre for step s+1 while (others) wait at the next barrier
        if (s + 1 < TT) {
            int len = len_s[gb];
            if (s + 1 < len) {
                int ta = dir ? (len - 2 - s) : (s + 1);
                const f16* xp = xpre + (size_t)(gb * TT + ta) * 2048 + sl * 8 + u0;
                half2v g0 = *(const half2v*)(xp);
                half2v g1 = *(const half2v*)(xp + 512);
                half2v g2 = *(const half2v*)(xp + 1024);
                half2v g3 = *(const half2v*)(xp + 1536);
                pr[0][0] = (float)g0[0]; pr[1][0] = (float)g0[1];
                pr[0][1] = (float)g1[0]; pr[1][1] = (float)g1[1];
                pr[0][2] = (float)g2[0]; pr[1][2] = (float)g2[1];
                pr[0][3] = (float)g3[0]; pr[1][3] = (float)g3[1];
            }
        }
    }
}

// ---------------------------------------------------------------------------
extern "C" void kernel_launch(void* const* d_in, const int* in_sizes, int n_in,
                              void* d_out, int out_size, void* d_ws, size_t ws_size,
                              hipStream_t stream) {
    const int* x = (const int*)d_in[0];
    const int* lengths = (const int*)d_in[1];
    const float* emb = (const float*)d_in[2];
    const float* w_ih_f1 = (const float*)d_in[3];
    const float* w_hh_f1 = (const float*)d_in[4];
    const float* b_f1 = (const float*)d_in[5];
    const float* w_ih_b1 = (const float*)d_in[6];
    const float* w_hh_b1 = (const float*)d_in[7];
    const float* b_b1 = (const float*)d_in[8];
    const float* w_ih_f2 = (const float*)d_in[9];
    const float* w_hh_f2 = (const float*)d_in[10];
    const float* b_f2 = (const float*)d_in[11];
    const float* w_ih_b2 = (const float*)d_in[12];
    const float* w_hh_b2 = (const float*)d_in[13];
    const float* b_b2 = (const float*)d_in[14];
    const float* cls_w = (const float*)d_in[15];
    const float* cls_b = (const float*)d_in[16];
    float* logits = (float*)d_out;

    // workspace layout (bytes) — max touched offset ~176 MB (proven envelope)
    char* ws = (char*)d_ws;
    int* bar = (int*)ws;                        // 0 .. 4 KB
    bf16* hbuf = (bf16*)(ws + 4096);            // 4 KB .. ~1.05 MB
    f16* e = (f16*)(ws + 2097152);              // 2 MB .. 10 MB
    f16* xpre_f = (f16*)(ws + 16777216);        // 16 MB .. 80 MB
    f16* xpre_b = (f16*)(ws + 83886080);        // 80 MB .. 144 MB
    f16* out1 = (f16*)(ws + 150994944);         // 144 MB .. 176 MB
    f16* out2 = out1;  // alias: out1 dead once layer-2 GEMMs complete

    bar_init<<<1, 64, 0, stream>>>(bar);
    embed_gather<<<BT / 4, 256, 0, stream>>>(x, emb, e);

    dim3 g1(BT / 128, 2048 / 128);
    gemm_bt<<<g1, 256, 0, stream>>>(e, w_ih_f1, b_f1, xpre_f, BT, 2048, EE);
    gemm_bt<<<g1, 256, 0, stream>>>(e, w_ih_b1, b_b1, xpre_b, BT, 2048, EE);
    lstm_scan<<<SBLK, 256, 0, stream>>>(xpre_f, xpre_b, w_hh_f1, w_hh_b1,
                                        lengths, out1, hbuf, bar, 0);

    gemm_bt<<<g1, 256, 0, stream>>>(out1, w_ih_f2, b_f2, xpre_f, BT, 2048, 2 * HH);
    gemm_bt<<<g1, 256, 0, stream>>>(out1, w_ih_b2, b_b2, xpre_b, BT, 2048, 2 * HH);
    lstm_scan<<<SBLK, 256, 0, stream>>>(xpre_f, xpre_b, w_hh_f2, w_hh_b2,
                                        lengths, out2, hbuf, bar, TT);

    cls_gemm<<<BT / 128, 256, 0, stream>>>(out2, cls_w, cls_b, logits);
}